// Round 1
// baseline (3701.842 us; speedup 1.0000x reference)
//
#include <hip/hip_runtime.h>

// Problem constants (from reference)
#define NGRAPH 16384          // B*T graphs
#define NG     23             // nodes per graph
#define HD     64             // hidden dim
#define INF    8              // input feature dim
#define LAYERS 20
#define EDGES_PER 256
#define E_TOT  (NGRAPH * EDGES_PER)
#define BATCH  1024
#define TWIN   16
#define CLS    3

// Main-kernel tiling
#define GPB     8             // graphs per 256-thread block (184 active lanes, wave 3 idles)
#define ACT     (GPB * NG)    // 184
#define ZSTRIDE 68            // LDS row stride (dwords): 16B-aligned, full-BW b128 pattern

// ---------------------------------------------------------------------------
// Kernel 1: edge list -> per-graph 23x23 count matrix A[dst_local][src_local].
// Layer-invariant, so built once per launch. Edges of graph g are exactly
// [g*256, (g+1)*256) by construction (gid = repeat(arange, E_PER)).
// ---------------------------------------------------------------------------
__global__ __launch_bounds__(64) void build_adj(const int* __restrict__ ei,
                                                float* __restrict__ A) {
  __shared__ int cnt[NG * NG];
  const int g = blockIdx.x, t = threadIdx.x;
  for (int i = t; i < NG * NG; i += 64) cnt[i] = 0;
  __syncthreads();
  const int base = g * EDGES_PER;
  const int goff = g * NG;
#pragma unroll
  for (int r = 0; r < EDGES_PER / 64; ++r) {
    const int e  = base + r * 64 + t;
    const int sl = ei[e] - goff;           // src local
    const int dl = ei[E_TOT + e] - goff;   // dst local
    atomicAdd(&cnt[dl * NG + sl], 1);
  }
  __syncthreads();
  for (int i = t; i < NG * NG; i += 64)
    A[(size_t)g * (NG * NG) + i] = (float)cnt[i];
}

// ---------------------------------------------------------------------------
// Kernel 2: fused encoder + 20 DeepGCN layers + node-sum pool, one lane per
// node, h[64] resident in VGPRs for the whole depth. W elements are
// wave-uniform -> scalar loads feeding v_fma (1 SGPR operand per FMA).
// ---------------------------------------------------------------------------
__global__ __launch_bounds__(256) void gcn_main(
    const float* __restrict__ x,     const float* __restrict__ A,
    const float* __restrict__ W_enc, const float* __restrict__ b_enc,
    const float* __restrict__ ln_g,  const float* __restrict__ ln_b,
    const float* __restrict__ W_rel, const float* __restrict__ b_rel,
    const float* __restrict__ W_root, float* __restrict__ pooled) {
  __shared__ float zbuf[ACT * ZSTRIDE];   // 184*68*4 = 50048 B
  const int t = threadIdx.x;
  const bool active = (t < ACT);
  const int s = t / NG;            // graph slot in block
  const int n = t - s * NG;        // node within graph
  const int g = blockIdx.x * GPB + s;

  float h[HD];
  float Ar[NG];

  if (active) {
    // ---- node encoder: h = x @ W_enc + b_enc ----
    float xi[INF];
    const float* xp = x + ((size_t)g * NG + n) * INF;
#pragma unroll
    for (int i = 0; i < INF; ++i) xi[i] = xp[i];
#pragma unroll
    for (int j = 0; j < HD; ++j) {
      float a = b_enc[j];
#pragma unroll
      for (int i = 0; i < INF; ++i) a = fmaf(xi[i], W_enc[i * HD + j], a);
      h[j] = a;
    }
    // ---- this node's adjacency row (layer-invariant) ----
    const float* Ap = A + (size_t)g * (NG * NG) + n * NG;
#pragma unroll
    for (int m = 0; m < NG; ++m) Ar[m] = Ap[m];
  }

#pragma unroll 1
  for (int l = 0; l < LAYERS; ++l) {
    const float* gl = ln_g + l * HD;
    const float* bl = ln_b + l * HD;
    const float* br = b_rel + l * HD;
    const float* Wr = W_rel + (size_t)l * HD * HD;
    const float* Wo = W_root + (size_t)l * HD * HD;

    if (active) {
      // ---- LayerNorm (in-lane) + relu -> z, staged to LDS ----
      float s0 = 0.f, s1 = 0.f, s2 = 0.f, s3 = 0.f;
#pragma unroll
      for (int k = 0; k < HD; k += 4) { s0 += h[k]; s1 += h[k+1]; s2 += h[k+2]; s3 += h[k+3]; }
      const float mu = (s0 + s1 + s2 + s3) * (1.0f / HD);
      float v0 = 0.f, v1 = 0.f, v2 = 0.f, v3 = 0.f;
#pragma unroll
      for (int k = 0; k < HD; k += 4) {
        const float d0 = h[k] - mu, d1 = h[k+1] - mu, d2 = h[k+2] - mu, d3 = h[k+3] - mu;
        v0 = fmaf(d0, d0, v0); v1 = fmaf(d1, d1, v1);
        v2 = fmaf(d2, d2, v2); v3 = fmaf(d3, d3, v3);
      }
      const float rs = rsqrtf((v0 + v1 + v2 + v3) * (1.0f / HD) + 1e-5f);
      float* zrow = &zbuf[t * ZSTRIDE];
#pragma unroll
      for (int q = 0; q < HD / 4; ++q) {
        float4 z4;
        z4.x = fmaxf(0.f, fmaf((h[4*q+0] - mu) * rs, gl[4*q+0], bl[4*q+0]));
        z4.y = fmaxf(0.f, fmaf((h[4*q+1] - mu) * rs, gl[4*q+1], bl[4*q+1]));
        z4.z = fmaxf(0.f, fmaf((h[4*q+2] - mu) * rs, gl[4*q+2], bl[4*q+2]));
        z4.w = fmaxf(0.f, fmaf((h[4*q+3] - mu) * rs, gl[4*q+3], bl[4*q+3]));
        *(float4*)(zrow + 4 * q) = z4;
      }
    }
    __syncthreads();

    if (active) {
      const float* zg   = &zbuf[(s * NG) * ZSTRIDE];  // this graph's z rows
      const float* zrow = &zbuf[t * ZSTRIDE];
#pragma unroll 1
      for (int q = 0; q < HD / 4; ++q) {
        // agg quad: agg[n][4q..4q+3] = sum_m A[n][m] * z[m][4q..4q+3]
        float a0 = 0.f, a1 = 0.f, a2 = 0.f, a3 = 0.f;
#pragma unroll
        for (int m = 0; m < NG; ++m) {
          const float4 zm = *(const float4*)(zg + m * ZSTRIDE + 4 * q);  // broadcast read
          const float am = Ar[m];
          a0 = fmaf(am, zm.x, a0); a1 = fmaf(am, zm.y, a1);
          a2 = fmaf(am, zm.z, a2); a3 = fmaf(am, zm.w, a3);
        }
        const float4 zn = *(const float4*)(zrow + 4 * q);  // own z quad
        const float aq[4] = {a0, a1, a2, a3};
        const float zq[4] = {zn.x, zn.y, zn.z, zn.w};
#pragma unroll
        for (int c = 0; c < 4; ++c) {
          const int k = 4 * q + c;
          const float* wrk = Wr + k * HD;   // wave-uniform -> s_load
          const float* wok = Wo + k * HD;
          const float ac = aq[c], zc = zq[c];
#pragma unroll
          for (int j = 0; j < HD; ++j)
            h[j] = fmaf(ac, wrk[j], fmaf(zc, wok[j], h[j]));
        }
      }
#pragma unroll
      for (int j = 0; j < HD; ++j) h[j] += br[j];   // + b_rel (residual form)
    }
    __syncthreads();
  }

  // ---- per-graph node-sum pool (divide by NG*T in head kernel) ----
  if (active) {
    float* zrow = &zbuf[t * ZSTRIDE];
#pragma unroll
    for (int q = 0; q < HD / 4; ++q) {
      float4 h4;
      h4.x = h[4*q+0]; h4.y = h[4*q+1]; h4.z = h[4*q+2]; h4.w = h[4*q+3];
      *(float4*)(zrow + 4 * q) = h4;
    }
  }
  __syncthreads();
  for (int o = t; o < GPB * HD; o += 256) {
    const int ss = o >> 6, k = o & 63;
    float sum = 0.f;
    for (int m = 0; m < NG; ++m) sum += zbuf[(ss * NG + m) * ZSTRIDE + k];
    pooled[((size_t)blockIdx.x * GPB + ss) * HD + k] = sum;
  }
}

// ---------------------------------------------------------------------------
// Kernel 3: temporal mean (+pos) + 2-layer MLP head -> [B, 3]
// ---------------------------------------------------------------------------
__global__ __launch_bounds__(64) void head(
    const float* __restrict__ pooled, const float* __restrict__ pos,
    const float* __restrict__ W1, const float* __restrict__ b1,
    const float* __restrict__ W2, const float* __restrict__ b2,
    float* __restrict__ out) {
  __shared__ float sv[HD];
  __shared__ float sh1[HD];
  const int b = blockIdx.x, k = threadIdx.x;

  float v = 0.f;
#pragma unroll
  for (int tt = 0; tt < TWIN; ++tt) v += pooled[((size_t)(b * TWIN + tt)) * HD + k];
  float p = 0.f;
#pragma unroll
  for (int tt = 0; tt < TWIN; ++tt) p += pos[tt * HD + k];
  v = v * (1.0f / (NG * TWIN)) + p * (1.0f / TWIN);

  sv[k] = v;
  __syncthreads();

  float a = b1[k];
#pragma unroll
  for (int kk = 0; kk < HD; ++kk) a = fmaf(sv[kk], W1[kk * HD + k], a);
  a = fmaxf(a, 0.f);
  sh1[k] = a;
  __syncthreads();

  if (k < CLS) {
    float o = b2[k];
#pragma unroll
    for (int kk = 0; kk < HD; ++kk) o = fmaf(sh1[kk], W2[kk * CLS + k], o);
    out[(size_t)b * CLS + k] = o;
  }
}

// ---------------------------------------------------------------------------
extern "C" void kernel_launch(void* const* d_in, const int* in_sizes, int n_in,
                              void* d_out, int out_size, void* d_ws, size_t ws_size,
                              hipStream_t stream) {
  const float* x      = (const float*)d_in[0];
  const int*   ei     = (const int*)  d_in[1];
  // d_in[2] = batch: unused (graphs have fixed NG nodes, contiguous ids)
  const float* W_enc  = (const float*)d_in[3];
  const float* b_enc  = (const float*)d_in[4];
  const float* ln_g   = (const float*)d_in[5];
  const float* ln_b   = (const float*)d_in[6];
  const float* W_rel  = (const float*)d_in[7];
  const float* b_rel  = (const float*)d_in[8];
  const float* W_root = (const float*)d_in[9];
  const float* pos    = (const float*)d_in[10];
  const float* W1     = (const float*)d_in[11];
  const float* b1     = (const float*)d_in[12];
  const float* W2     = (const float*)d_in[13];
  const float* b2     = (const float*)d_in[14];
  float* out = (float*)d_out;

  // workspace: A (16384*529 fp32 = 34.7 MB) | pooled (16384*64 fp32 = 4.2 MB)
  float* A      = (float*)d_ws;
  float* pooled = A + (size_t)NGRAPH * NG * NG;

  build_adj<<<NGRAPH, 64, 0, stream>>>(ei, A);
  gcn_main<<<NGRAPH / GPB, 256, 0, stream>>>(x, A, W_enc, b_enc, ln_g, ln_b,
                                             W_rel, b_rel, W_root, pooled);
  head<<<BATCH, 64, 0, stream>>>(pooled, pos, W1, b1, W2, b2, out);
}

// Round 2
// 703.871 us; speedup vs baseline: 5.2593x; 5.2593x over previous
//
#include <hip/hip_runtime.h>

// Problem constants
#define NGRAPH 16384
#define NG     23
#define HD     64
#define INF    8
#define LAYERS 20
#define EDGES_PER 256
#define E_TOT  (NGRAPH * EDGES_PER)
#define BATCH  1024
#define TWIN   16
#define CLS    3

// LDS geometry: per-node row of bf16 dims. DP=72 keeps b128 rows 16B-aligned.
#define DP        72
#define WAVE_LDSE (2 * 32 * DP)   // ushorts per wave: zbuf + aggbuf = 9216 B

typedef __attribute__((ext_vector_type(8))) short s8v;   // 8 bf16 (4 VGPRs) MFMA A/B frag
typedef __attribute__((ext_vector_type(4))) float f4v;   // 4 fp32 MFMA C/D frag

union FragU { unsigned u[4]; s8v v; };

// RNE f32->bf16, two values packed into one dword (lo = a, hi = b)
__device__ inline unsigned f2bf_pk(float a, float b) {
  unsigned ua = __builtin_bit_cast(unsigned, a);
  unsigned ub = __builtin_bit_cast(unsigned, b);
  ua = ua + 0x7FFFu + ((ua >> 16) & 1u);
  ub = ub + 0x7FFFu + ((ub >> 16) & 1u);
  return (ua >> 16) | (ub & 0xFFFF0000u);
}

// ---------------------------------------------------------------------------
// Kernel 1: edges -> adjacency B-frags (A^T as B-operand, bf16, pad-zeroed).
// B-frag lane map (16x16x32): value = A[dst = (lane&15)+16*Nt][src = quad*8+j].
// ---------------------------------------------------------------------------
__global__ __launch_bounds__(256) void build_adj(const int* __restrict__ ei,
                                                 unsigned* __restrict__ adjf) {
  __shared__ int cnt[4][NG * NG];
  const int grp = threadIdx.x >> 6, lane = threadIdx.x & 63;
  const int g = blockIdx.x * 4 + grp;
  for (int i = lane; i < NG * NG; i += 64) cnt[grp][i] = 0;
  __syncthreads();
  const int base = g * EDGES_PER, goff = g * NG;
#pragma unroll
  for (int r = 0; r < EDGES_PER / 64; ++r) {
    const int e = base + r * 64 + lane;
    atomicAdd(&cnt[grp][(ei[E_TOT + e] - goff) * NG + (ei[e] - goff)], 1);
  }
  __syncthreads();
  const int col = lane & 15, quad = lane >> 4;
#pragma unroll
  for (int Nt = 0; Nt < 2; ++Nt) {
    const int dst = col + 16 * Nt;
    unsigned pk[4];
#pragma unroll
    for (int w = 0; w < 4; ++w) {
      const int s0 = quad * 8 + 2 * w, s1 = s0 + 1;
      float v0 = 0.f, v1 = 0.f;
      if (dst < NG) {
        if (s0 < NG) v0 = (float)cnt[grp][dst * NG + s0];
        if (s1 < NG) v1 = (float)cnt[grp][dst * NG + s1];
      }
      pk[w] = f2bf_pk(v0, v1);
    }
    uint4 q; q.x = pk[0]; q.y = pk[1]; q.z = pk[2]; q.w = pk[3];
    *(uint4*)&adjf[(((size_t)g * 2 + Nt) * 64 + lane) * 4] = q;
  }
}

// ---------------------------------------------------------------------------
// Kernel 2: pack W^T into A-frag lane order (bf16), one dwordx4 per frag-lane.
// A-frag value = W^T[m][k] = W[k = Kt*32+quad*8+j][ m = Mt*16+(lane&15) ].
// ---------------------------------------------------------------------------
__global__ __launch_bounds__(256) void pack_w(const float* __restrict__ W_rel,
                                              const float* __restrict__ W_root,
                                              unsigned* __restrict__ wf) {
  const int tid = blockIdx.x * 256 + threadIdx.x;
  if (tid >= LAYERS * 2 * 4 * 2 * 64) return;
  const int lane = tid & 63, fi = tid >> 6;
  const int Kt = fi & 1, Mt = (fi >> 1) & 3, m = (fi >> 3) & 1, l = fi >> 4;
  const float* W = (m ? W_root : W_rel) + (size_t)l * HD * HD;
  const int col = lane & 15, quad = lane >> 4;
  const int jdim = Mt * 16 + col;
  unsigned pk[4];
#pragma unroll
  for (int w = 0; w < 4; ++w) {
    const int k0 = Kt * 32 + quad * 8 + 2 * w;
    pk[w] = f2bf_pk(W[(size_t)k0 * HD + jdim], W[(size_t)(k0 + 1) * HD + jdim]);
  }
  uint4 q; q.x = pk[0]; q.y = pk[1]; q.z = pk[2]; q.w = pk[3];
  *(uint4*)&wf[(size_t)tid * 4] = q;
}

// ---------------------------------------------------------------------------
// Kernel 3: wave = 1 graph. State H[dim][node] in 8 fp32 C-frags, 20 layers
// via MFMA: AGG = Z @ A^T ; H += Wr^T @ AGG + Wo^T @ Z (+br). No __syncthreads
// (waves independent); intra-wave LDS relayouts fenced with lgkmcnt(0).
// ---------------------------------------------------------------------------
__global__ __launch_bounds__(256) void gcn_main(
    const float* __restrict__ x, const unsigned* __restrict__ adjf,
    const unsigned* __restrict__ wf,
    const float* __restrict__ W_enc, const float* __restrict__ b_enc,
    const float* __restrict__ ln_g, const float* __restrict__ ln_b,
    const float* __restrict__ b_rel, float* __restrict__ pooled) {
  __shared__ unsigned short sm[4 * WAVE_LDSE];   // 36.9 KB/block
  const int lane = threadIdx.x & 63, wv = threadIdx.x >> 6;
  const int g = blockIdx.x * 4 + wv;
  const int col = lane & 15, quad = lane >> 4;
  unsigned short* zb = sm + wv * WAVE_LDSE;
  unsigned short* ab = zb + 32 * DP;

  // adjacency B-frags, persistent across layers
  s8v adjB0 = *(const s8v*)&adjf[(((size_t)g * 2 + 0) * 64 + lane) * 4];
  s8v adjB1 = *(const s8v*)&adjf[(((size_t)g * 2 + 1) * 64 + lane) * 4];

  // ---- encoder: H[d][n] = sum_i W_enc[i][d] x[n][i] + b_enc[d] ----
  f4v acc[4][2];
  {
    f4v xa[2][2];
    const f4v zz = {0.f, 0.f, 0.f, 0.f};
#pragma unroll
    for (int Nt = 0; Nt < 2; ++Nt) {
      const int n = col + 16 * Nt;
      if (n < NG) {
        const float* xp = x + ((size_t)g * NG + n) * INF;
        xa[Nt][0] = *(const f4v*)xp;
        xa[Nt][1] = *(const f4v*)(xp + 4);
      } else { xa[Nt][0] = zz; xa[Nt][1] = zz; }
    }
#pragma unroll
    for (int Mt = 0; Mt < 4; ++Mt) {
      const f4v be = *(const f4v*)(b_enc + Mt * 16 + quad * 4);
      acc[Mt][0] = be; acc[Mt][1] = be;
#pragma unroll
      for (int i = 0; i < INF; ++i) {
        const f4v we = *(const f4v*)(W_enc + i * HD + Mt * 16 + quad * 4);
        acc[Mt][0] += we * xa[0][i >> 2][i & 3];
        acc[Mt][1] += we * xa[1][i >> 2][i & 3];
      }
    }
  }

#pragma unroll 1
  for (int l = 0; l < LAYERS; ++l) {
    // per-layer params (fp32): dims of this lane are Mt*16 + quad*4 + r
    f4v gf[4], bfv[4], brf[4];
#pragma unroll
    for (int Mt = 0; Mt < 4; ++Mt) {
      gf[Mt]  = *(const f4v*)(ln_g  + l * HD + Mt * 16 + quad * 4);
      bfv[Mt] = *(const f4v*)(ln_b  + l * HD + Mt * 16 + quad * 4);
      brf[Mt] = *(const f4v*)(b_rel + l * HD + Mt * 16 + quad * 4);
    }

    // ---- LayerNorm per node-col (2-step cross-quad shuffle reduce) ----
    float mu[2], rs[2];
#pragma unroll
    for (int Nt = 0; Nt < 2; ++Nt) {
      float s = 0.f;
#pragma unroll
      for (int Mt = 0; Mt < 4; ++Mt)
        s += acc[Mt][Nt][0] + acc[Mt][Nt][1] + acc[Mt][Nt][2] + acc[Mt][Nt][3];
      s += __shfl_xor(s, 16); s += __shfl_xor(s, 32);
      mu[Nt] = s * (1.0f / HD);
      float v = 0.f;
#pragma unroll
      for (int Mt = 0; Mt < 4; ++Mt)
#pragma unroll
        for (int r = 0; r < 4; ++r) {
          const float d = acc[Mt][Nt][r] - mu[Nt];
          v = fmaf(d, d, v);
        }
      v += __shfl_xor(v, 16); v += __shfl_xor(v, 32);
      rs[Nt] = rsqrtf(v * (1.0f / HD) + 1e-5f);
    }

    // ---- z = relu(LN(h)) -> bf16 -> zbuf[node][dim] (ds_write_b64) ----
#pragma unroll
    for (int Mt = 0; Mt < 4; ++Mt)
#pragma unroll
      for (int Nt = 0; Nt < 2; ++Nt) {
        const f4v h = acc[Mt][Nt];
        const float z0 = fmaxf(0.f, fmaf((h[0] - mu[Nt]) * rs[Nt], gf[Mt][0], bfv[Mt][0]));
        const float z1 = fmaxf(0.f, fmaf((h[1] - mu[Nt]) * rs[Nt], gf[Mt][1], bfv[Mt][1]));
        const float z2 = fmaxf(0.f, fmaf((h[2] - mu[Nt]) * rs[Nt], gf[Mt][2], bfv[Mt][2]));
        const float z3 = fmaxf(0.f, fmaf((h[3] - mu[Nt]) * rs[Nt], gf[Mt][3], bfv[Mt][3]));
        uint2 t; t.x = f2bf_pk(z0, z1); t.y = f2bf_pk(z2, z3);
        const int n = col + 16 * Nt;
        *(uint2*)&zb[n * DP + Mt * 16 + quad * 4] = t;
      }
    asm volatile("s_waitcnt lgkmcnt(0)" ::: "memory");

    // ---- Z as A-frag (strided u16 transpose reads) ----
    FragU za[4];
#pragma unroll
    for (int Mt = 0; Mt < 4; ++Mt) {
      unsigned short tv[8];
#pragma unroll
      for (int j = 0; j < 8; ++j)
        tv[j] = zb[(quad * 8 + j) * DP + Mt * 16 + col];
#pragma unroll
      for (int w = 0; w < 4; ++w)
        za[Mt].u[w] = (unsigned)tv[2 * w] | ((unsigned)tv[2 * w + 1] << 16);
    }

    // ---- AGG = Z @ A^T (K=32, one MFMA step) ----
    const f4v zzero = {0.f, 0.f, 0.f, 0.f};
    f4v ag[4][2];
#pragma unroll
    for (int Mt = 0; Mt < 4; ++Mt) {
      ag[Mt][0] = __builtin_amdgcn_mfma_f32_16x16x32_bf16(za[Mt].v, adjB0, zzero, 0, 0, 0);
      ag[Mt][1] = __builtin_amdgcn_mfma_f32_16x16x32_bf16(za[Mt].v, adjB1, zzero, 0, 0, 0);
    }

    // ---- AGG -> bf16 -> aggbuf[dst][dim] ----
#pragma unroll
    for (int Mt = 0; Mt < 4; ++Mt)
#pragma unroll
      for (int Nt = 0; Nt < 2; ++Nt) {
        const f4v a4 = ag[Mt][Nt];
        uint2 t; t.x = f2bf_pk(a4[0], a4[1]); t.y = f2bf_pk(a4[2], a4[3]);
        const int n = col + 16 * Nt;
        *(uint2*)&ab[n * DP + Mt * 16 + quad * 4] = t;
      }
    asm volatile("s_waitcnt lgkmcnt(0)" ::: "memory");

    // ---- H += Wr^T @ AGG + Wo^T @ Z ----
#pragma unroll
    for (int Kt = 0; Kt < 2; ++Kt) {
      s8v Zb[2], Ab[2];
#pragma unroll
      for (int Nt = 0; Nt < 2; ++Nt) {
        const int off = (col + 16 * Nt) * DP + Kt * 32 + quad * 8;
        Zb[Nt] = *(const s8v*)&zb[off];
        Ab[Nt] = *(const s8v*)&ab[off];
      }
#pragma unroll
      for (int Mt = 0; Mt < 4; ++Mt) {
        const size_t fr = (size_t)((((l * 2 + 0) * 4 + Mt) * 2 + Kt) * 64 + lane) * 4;
        const size_t fo = (size_t)((((l * 2 + 1) * 4 + Mt) * 2 + Kt) * 64 + lane) * 4;
        const s8v wr = *(const s8v*)&wf[fr];
        const s8v wo = *(const s8v*)&wf[fo];
#pragma unroll
        for (int Nt = 0; Nt < 2; ++Nt) {
          acc[Mt][Nt] = __builtin_amdgcn_mfma_f32_16x16x32_bf16(wr, Ab[Nt], acc[Mt][Nt], 0, 0, 0);
          acc[Mt][Nt] = __builtin_amdgcn_mfma_f32_16x16x32_bf16(wo, Zb[Nt], acc[Mt][Nt], 0, 0, 0);
        }
      }
    }
    asm volatile("s_waitcnt lgkmcnt(0)" ::: "memory");

    // ---- + b_rel ----
#pragma unroll
    for (int Mt = 0; Mt < 4; ++Mt)
#pragma unroll
      for (int Nt = 0; Nt < 2; ++Nt)
        acc[Mt][Nt] += brf[Mt];
  }

  // ---- pool: sum over 23 real node-cols per dim ----
  float* hb = (float*)zb;   // 9216 B wave region >= 23*64*4
  asm volatile("s_waitcnt lgkmcnt(0)" ::: "memory");
#pragma unroll
  for (int Mt = 0; Mt < 4; ++Mt)
#pragma unroll
    for (int Nt = 0; Nt < 2; ++Nt) {
      const int n = col + 16 * Nt;
      if (n < NG) *(f4v*)&hb[n * HD + Mt * 16 + quad * 4] = acc[Mt][Nt];
    }
  asm volatile("s_waitcnt lgkmcnt(0)" ::: "memory");
  float s = 0.f;
#pragma unroll
  for (int n = 0; n < NG; ++n) s += hb[n * HD + lane];
  pooled[(size_t)g * HD + lane] = s;
}

// ---------------------------------------------------------------------------
// Kernel 4: temporal mean (+pos) + MLP head (unchanged, verified round 1)
// ---------------------------------------------------------------------------
__global__ __launch_bounds__(64) void head(
    const float* __restrict__ pooled, const float* __restrict__ pos,
    const float* __restrict__ W1, const float* __restrict__ b1,
    const float* __restrict__ W2, const float* __restrict__ b2,
    float* __restrict__ out) {
  __shared__ float sv[HD];
  __shared__ float sh1[HD];
  const int b = blockIdx.x, k = threadIdx.x;
  float v = 0.f;
#pragma unroll
  for (int tt = 0; tt < TWIN; ++tt) v += pooled[((size_t)(b * TWIN + tt)) * HD + k];
  float p = 0.f;
#pragma unroll
  for (int tt = 0; tt < TWIN; ++tt) p += pos[tt * HD + k];
  v = v * (1.0f / (NG * TWIN)) + p * (1.0f / TWIN);
  sv[k] = v;
  __syncthreads();
  float a = b1[k];
#pragma unroll
  for (int kk = 0; kk < HD; ++kk) a = fmaf(sv[kk], W1[kk * HD + k], a);
  a = fmaxf(a, 0.f);
  sh1[k] = a;
  __syncthreads();
  if (k < CLS) {
    float o = b2[k];
#pragma unroll
    for (int kk = 0; kk < HD; ++kk) o = fmaf(sh1[kk], W2[kk * CLS + k], o);
    out[(size_t)b * CLS + k] = o;
  }
}

// ---------------------------------------------------------------------------
extern "C" void kernel_launch(void* const* d_in, const int* in_sizes, int n_in,
                              void* d_out, int out_size, void* d_ws, size_t ws_size,
                              hipStream_t stream) {
  const float* x      = (const float*)d_in[0];
  const int*   ei     = (const int*)  d_in[1];
  const float* W_enc  = (const float*)d_in[3];
  const float* b_enc  = (const float*)d_in[4];
  const float* ln_g   = (const float*)d_in[5];
  const float* ln_b   = (const float*)d_in[6];
  const float* W_rel  = (const float*)d_in[7];
  const float* b_rel  = (const float*)d_in[8];
  const float* W_root = (const float*)d_in[9];
  const float* pos    = (const float*)d_in[10];
  const float* W1     = (const float*)d_in[11];
  const float* b1     = (const float*)d_in[12];
  const float* W2     = (const float*)d_in[13];
  const float* b2     = (const float*)d_in[14];
  float* out = (float*)d_out;

  // workspace: W frags 320 KB | adj frags 32 MB | pooled 4.2 MB  (~36.8 MB)
  char* p = (char*)d_ws;
  unsigned* wfrag   = (unsigned*)p;  p += (size_t)LAYERS * 2 * 4 * 2 * 64 * 16;
  unsigned* adjfrag = (unsigned*)p;  p += (size_t)NGRAPH * 2 * 64 * 16;
  float*    pooled  = (float*)p;

  pack_w   <<<80, 256, 0, stream>>>(W_rel, W_root, wfrag);
  build_adj<<<NGRAPH / 4, 256, 0, stream>>>(ei, adjfrag);
  gcn_main <<<NGRAPH / 4, 256, 0, stream>>>(x, adjfrag, wfrag, W_enc, b_enc,
                                            ln_g, ln_b, b_rel, pooled);
  head     <<<BATCH, 64, 0, stream>>>(pooled, pos, W1, b1, W2, b2, out);
}

// Round 4
// 667.687 us; speedup vs baseline: 5.5443x; 1.0542x over previous
//
#include <hip/hip_runtime.h>

// Problem constants
#define NGRAPH 16384
#define NG     23
#define HD     64
#define INF    8
#define LAYERS 20
#define EDGES_PER 256
#define E_TOT  (NGRAPH * EDGES_PER)
#define BATCH  1024
#define TWIN   16
#define CLS    3

// LDS geometry: per-node row of bf16 dims. DP=72 keeps b128 rows 16B-aligned.
#define DP        72
#define WAVE_LDSE (2 * 32 * DP)   // ushorts per wave: zbuf + aggbuf = 9216 B

typedef __attribute__((ext_vector_type(8))) short s8v;   // 8 bf16 (4 VGPRs) MFMA A/B frag
typedef __attribute__((ext_vector_type(4))) float f4v;   // 4 fp32 MFMA C/D frag

union FragU { unsigned u[4]; s8v v; };

// f32 -> packed bf16x2 (lo = a, hi = b), RNE.
// Guarded: HW packed-cvt builtin if this toolchain has it, else manual RNE
// (manual path is the round-2-verified code; compile-safe either way).
#if defined(__has_builtin)
#  if __has_builtin(__builtin_amdgcn_cvt_pk_bf16_f32)
#    define HAVE_CVT_PK_BF16 1
#  endif
#endif
#ifndef HAVE_CVT_PK_BF16
#  define HAVE_CVT_PK_BF16 0
#endif

__device__ inline unsigned f2bf_pk(float a, float b) {
  unsigned ua = __builtin_bit_cast(unsigned, a);
  unsigned ub = __builtin_bit_cast(unsigned, b);
  ua = ua + 0x7FFFu + ((ua >> 16) & 1u);
  ub = ub + 0x7FFFu + ((ub >> 16) & 1u);
  return (ua >> 16) | (ub & 0xFFFF0000u);
}

__device__ inline unsigned pk_bf16(float a, float b) {
#if HAVE_CVT_PK_BF16
  auto r = __builtin_amdgcn_cvt_pk_bf16_f32(a, b);   // D.lo=bf16(S0), D.hi=bf16(S1)
  static_assert(sizeof(r) == 4, "packed bf16x2 expected");
  return __builtin_bit_cast(unsigned, r);
#else
  return f2bf_pk(a, b);
#endif
}

// ---------------------------------------------------------------------------
// Kernel 1: edges -> adjacency B-frags (A^T as B-operand, bf16, pad-zeroed).
// B-frag lane map (16x16x32): value = A[dst = (lane&15)+16*Nt][src = quad*8+j].
// ---------------------------------------------------------------------------
__global__ __launch_bounds__(256) void build_adj(const int* __restrict__ ei,
                                                 unsigned* __restrict__ adjf) {
  __shared__ int cnt[4][NG * NG];
  const int grp = threadIdx.x >> 6, lane = threadIdx.x & 63;
  const int g = blockIdx.x * 4 + grp;
  for (int i = lane; i < NG * NG; i += 64) cnt[grp][i] = 0;
  __syncthreads();
  const int base = g * EDGES_PER, goff = g * NG;
#pragma unroll
  for (int r = 0; r < EDGES_PER / 64; ++r) {
    const int e = base + r * 64 + lane;
    atomicAdd(&cnt[grp][(ei[E_TOT + e] - goff) * NG + (ei[e] - goff)], 1);
  }
  __syncthreads();
  const int col = lane & 15, quad = lane >> 4;
#pragma unroll
  for (int Nt = 0; Nt < 2; ++Nt) {
    const int dst = col + 16 * Nt;
    unsigned pk[4];
#pragma unroll
    for (int w = 0; w < 4; ++w) {
      const int s0 = quad * 8 + 2 * w, s1 = s0 + 1;
      float v0 = 0.f, v1 = 0.f;
      if (dst < NG) {
        if (s0 < NG) v0 = (float)cnt[grp][dst * NG + s0];
        if (s1 < NG) v1 = (float)cnt[grp][dst * NG + s1];
      }
      pk[w] = f2bf_pk(v0, v1);
    }
    uint4 q; q.x = pk[0]; q.y = pk[1]; q.z = pk[2]; q.w = pk[3];
    *(uint4*)&adjf[(((size_t)g * 2 + Nt) * 64 + lane) * 4] = q;
  }
}

// ---------------------------------------------------------------------------
// Kernel 2: pack W^T into A-frag lane order (bf16), one dwordx4 per frag-lane.
// A-frag value = W^T[m][k] = W[k = Kt*32+quad*8+j][ m = Mt*16+(lane&15) ].
// ---------------------------------------------------------------------------
__global__ __launch_bounds__(256) void pack_w(const float* __restrict__ W_rel,
                                              const float* __restrict__ W_root,
                                              unsigned* __restrict__ wf) {
  const int tid = blockIdx.x * 256 + threadIdx.x;
  if (tid >= LAYERS * 2 * 4 * 2 * 64) return;
  const int lane = tid & 63, fi = tid >> 6;
  const int Kt = fi & 1, Mt = (fi >> 1) & 3, m = (fi >> 3) & 1, l = fi >> 4;
  const float* W = (m ? W_root : W_rel) + (size_t)l * HD * HD;
  const int col = lane & 15, quad = lane >> 4;
  const int jdim = Mt * 16 + col;
  unsigned pk[4];
#pragma unroll
  for (int w = 0; w < 4; ++w) {
    const int k0 = Kt * 32 + quad * 8 + 2 * w;
    pk[w] = f2bf_pk(W[(size_t)k0 * HD + jdim], W[(size_t)(k0 + 1) * HD + jdim]);
  }
  uint4 q; q.x = pk[0]; q.y = pk[1]; q.z = pk[2]; q.w = pk[3];
  *(uint4*)&wf[(size_t)tid * 4] = q;
}

// ---------------------------------------------------------------------------
// Kernel 3: wave = 1 graph. State H[dim][node] in 8 fp32 C-frags, 20 layers
// via MFMA: AGG = Z @ A^T ; H += Wr^T @ AGG + Wo^T @ Z (+br). No __syncthreads
// (waves independent); intra-wave LDS relayouts fenced with lgkmcnt(0).
// ---------------------------------------------------------------------------
__global__ __launch_bounds__(256) void gcn_main(
    const float* __restrict__ x, const unsigned* __restrict__ adjf,
    const unsigned* __restrict__ wf,
    const float* __restrict__ W_enc, const float* __restrict__ b_enc,
    const float* __restrict__ ln_g, const float* __restrict__ ln_b,
    const float* __restrict__ b_rel, float* __restrict__ pooled) {
  __shared__ unsigned short sm[4 * WAVE_LDSE];   // 36.9 KB/block
  const int lane = threadIdx.x & 63, wv = threadIdx.x >> 6;
  const int g = blockIdx.x * 4 + wv;
  const int col = lane & 15, quad = lane >> 4;
  unsigned short* zb = sm + wv * WAVE_LDSE;
  unsigned short* ab = zb + 32 * DP;

  // adjacency B-frags, persistent across layers
  s8v adjB0 = *(const s8v*)&adjf[(((size_t)g * 2 + 0) * 64 + lane) * 4];
  s8v adjB1 = *(const s8v*)&adjf[(((size_t)g * 2 + 1) * 64 + lane) * 4];

  // ---- encoder: H[d][n] = sum_i W_enc[i][d] x[n][i] + b_enc[d] ----
  f4v acc[4][2];
  {
    f4v xa[2][2];
    const f4v zz = {0.f, 0.f, 0.f, 0.f};
#pragma unroll
    for (int Nt = 0; Nt < 2; ++Nt) {
      const int n = col + 16 * Nt;
      if (n < NG) {
        const float* xp = x + ((size_t)g * NG + n) * INF;
        xa[Nt][0] = *(const f4v*)xp;
        xa[Nt][1] = *(const f4v*)(xp + 4);
      } else { xa[Nt][0] = zz; xa[Nt][1] = zz; }
    }
#pragma unroll
    for (int Mt = 0; Mt < 4; ++Mt) {
      const f4v be = *(const f4v*)(b_enc + Mt * 16 + quad * 4);
      acc[Mt][0] = be; acc[Mt][1] = be;
#pragma unroll
      for (int i = 0; i < INF; ++i) {
        const f4v we = *(const f4v*)(W_enc + i * HD + Mt * 16 + quad * 4);
        acc[Mt][0] += we * xa[0][i >> 2][i & 3];
        acc[Mt][1] += we * xa[1][i >> 2][i & 3];
      }
    }
  }

#pragma unroll 1
  for (int l = 0; l < LAYERS; ++l) {
    // per-layer params (uniform -> s_load); lane dims = Mt*16 + quad*4 + r
    f4v gf[4], bfv[4], brf[4];
#pragma unroll
    for (int Mt = 0; Mt < 4; ++Mt) {
      gf[Mt]  = *(const f4v*)(ln_g  + l * HD + Mt * 16 + quad * 4);
      bfv[Mt] = *(const f4v*)(ln_b  + l * HD + Mt * 16 + quad * 4);
      brf[Mt] = *(const f4v*)(b_rel + l * HD + Mt * 16 + quad * 4);
    }

    // ---- LayerNorm per node-col: one-pass E[h], E[h^2], f4v-vectorized ----
    float mu[2], rs[2];
    {
      float sh[2], qh[2];
#pragma unroll
      for (int Nt = 0; Nt < 2; ++Nt) {
        f4v t = acc[0][Nt] + acc[1][Nt];
        t += acc[2][Nt]; t += acc[3][Nt];
        f4v u = acc[0][Nt] * acc[0][Nt];
        u += acc[1][Nt] * acc[1][Nt];
        u += acc[2][Nt] * acc[2][Nt];
        u += acc[3][Nt] * acc[3][Nt];
        sh[Nt] = (t[0] + t[1]) + (t[2] + t[3]);
        qh[Nt] = (u[0] + u[1]) + (u[2] + u[3]);
      }
      // interleave both Nt shuffle chains
      sh[0] += __shfl_xor(sh[0], 16); sh[1] += __shfl_xor(sh[1], 16);
      qh[0] += __shfl_xor(qh[0], 16); qh[1] += __shfl_xor(qh[1], 16);
      sh[0] += __shfl_xor(sh[0], 32); sh[1] += __shfl_xor(sh[1], 32);
      qh[0] += __shfl_xor(qh[0], 32); qh[1] += __shfl_xor(qh[1], 32);
#pragma unroll
      for (int Nt = 0; Nt < 2; ++Nt) {
        mu[Nt] = sh[Nt] * (1.0f / HD);
        float var = fmaf(qh[Nt], (1.0f / HD), -mu[Nt] * mu[Nt]);
        var = fmaxf(var, 0.f);   // cancellation insurance (pad cols are exact 0)
        rs[Nt] = rsqrtf(var + 1e-5f);
      }
    }

    // ---- z = relu(h*(rs*g) + (b - mu*rs*g)) -> bf16 -> zbuf[node][dim] ----
#pragma unroll
    for (int Nt = 0; Nt < 2; ++Nt) {
      const int n = col + 16 * Nt;
#pragma unroll
      for (int Mt = 0; Mt < 4; ++Mt) {
        const f4v sg = gf[Mt] * rs[Nt];
        const f4v tb = bfv[Mt] - mu[Nt] * sg;
        f4v z4 = acc[Mt][Nt] * sg + tb;
        z4[0] = fmaxf(z4[0], 0.f); z4[1] = fmaxf(z4[1], 0.f);
        z4[2] = fmaxf(z4[2], 0.f); z4[3] = fmaxf(z4[3], 0.f);
        uint2 t; t.x = pk_bf16(z4[0], z4[1]); t.y = pk_bf16(z4[2], z4[3]);
        *(uint2*)&zb[n * DP + Mt * 16 + quad * 4] = t;
      }
    }
    asm volatile("s_waitcnt lgkmcnt(0)" ::: "memory");

    // ---- Z as A-frag (strided u16 transpose reads) ----
    FragU za[4];
#pragma unroll
    for (int Mt = 0; Mt < 4; ++Mt) {
      unsigned short tv[8];
#pragma unroll
      for (int j = 0; j < 8; ++j)
        tv[j] = zb[(quad * 8 + j) * DP + Mt * 16 + col];
#pragma unroll
      for (int w = 0; w < 4; ++w)
        za[Mt].u[w] = (unsigned)tv[2 * w] | ((unsigned)tv[2 * w + 1] << 16);
    }

    // ---- Zb B-frags early (b128s land during agg MFMA window) ----
    s8v Zb[2][2];
#pragma unroll
    for (int Kt = 0; Kt < 2; ++Kt)
#pragma unroll
      for (int Nt = 0; Nt < 2; ++Nt)
        Zb[Kt][Nt] = *(const s8v*)&zb[(col + 16 * Nt) * DP + Kt * 32 + quad * 8];

    // ---- AGG = Z @ A^T (K=32, one MFMA step) ----
    const f4v zzero = {0.f, 0.f, 0.f, 0.f};
    f4v ag[4][2];
#pragma unroll
    for (int Mt = 0; Mt < 4; ++Mt) {
      ag[Mt][0] = __builtin_amdgcn_mfma_f32_16x16x32_bf16(za[Mt].v, adjB0, zzero, 0, 0, 0);
      ag[Mt][1] = __builtin_amdgcn_mfma_f32_16x16x32_bf16(za[Mt].v, adjB1, zzero, 0, 0, 0);
    }

    // ---- AGG -> bf16 -> aggbuf[dst][dim] ----
#pragma unroll
    for (int Mt = 0; Mt < 4; ++Mt)
#pragma unroll
      for (int Nt = 0; Nt < 2; ++Nt) {
        const f4v a4 = ag[Mt][Nt];
        uint2 t; t.x = pk_bf16(a4[0], a4[1]); t.y = pk_bf16(a4[2], a4[3]);
        *(uint2*)&ab[(col + 16 * Nt) * DP + Mt * 16 + quad * 4] = t;
      }
    asm volatile("s_waitcnt lgkmcnt(0)" ::: "memory");

    // ---- H += Wr^T @ AGG + Wo^T @ Z ----
#pragma unroll
    for (int Kt = 0; Kt < 2; ++Kt) {
      s8v Ab[2];
#pragma unroll
      for (int Nt = 0; Nt < 2; ++Nt)
        Ab[Nt] = *(const s8v*)&ab[(col + 16 * Nt) * DP + Kt * 32 + quad * 8];
#pragma unroll
      for (int Mt = 0; Mt < 4; ++Mt) {
        const size_t fr = (size_t)((((l * 2 + 0) * 4 + Mt) * 2 + Kt) * 64 + lane) * 4;
        const size_t fo = (size_t)((((l * 2 + 1) * 4 + Mt) * 2 + Kt) * 64 + lane) * 4;
        const s8v wr = *(const s8v*)&wf[fr];
        const s8v wo = *(const s8v*)&wf[fo];
#pragma unroll
        for (int Nt = 0; Nt < 2; ++Nt) {
          acc[Mt][Nt] = __builtin_amdgcn_mfma_f32_16x16x32_bf16(wr, Ab[Nt], acc[Mt][Nt], 0, 0, 0);
          acc[Mt][Nt] = __builtin_amdgcn_mfma_f32_16x16x32_bf16(wo, Zb[Kt][Nt], acc[Mt][Nt], 0, 0, 0);
        }
      }
    }
    asm volatile("s_waitcnt lgkmcnt(0)" ::: "memory");

    // ---- + b_rel ----
#pragma unroll
    for (int Mt = 0; Mt < 4; ++Mt) {
      acc[Mt][0] += brf[Mt];
      acc[Mt][1] += brf[Mt];
    }
  }

  // ---- pool: sum over 23 real node-cols per dim ----
  float* hb = (float*)zb;   // 9216 B wave region >= 23*64*4
  asm volatile("s_waitcnt lgkmcnt(0)" ::: "memory");
#pragma unroll
  for (int Mt = 0; Mt < 4; ++Mt)
#pragma unroll
    for (int Nt = 0; Nt < 2; ++Nt) {
      const int n = col + 16 * Nt;
      if (n < NG) *(f4v*)&hb[n * HD + Mt * 16 + quad * 4] = acc[Mt][Nt];
    }
  asm volatile("s_waitcnt lgkmcnt(0)" ::: "memory");
  float s = 0.f;
#pragma unroll
  for (int n = 0; n < NG; ++n) s += hb[n * HD + lane];
  pooled[(size_t)g * HD + lane] = s;
}

// ---------------------------------------------------------------------------
// Kernel 4: temporal mean (+pos) + MLP head
// ---------------------------------------------------------------------------
__global__ __launch_bounds__(64) void head(
    const float* __restrict__ pooled, const float* __restrict__ pos,
    const float* __restrict__ W1, const float* __restrict__ b1,
    const float* __restrict__ W2, const float* __restrict__ b2,
    float* __restrict__ out) {
  __shared__ float sv[HD];
  __shared__ float sh1[HD];
  const int b = blockIdx.x, k = threadIdx.x;
  float v = 0.f;
#pragma unroll
  for (int tt = 0; tt < TWIN; ++tt) v += pooled[((size_t)(b * TWIN + tt)) * HD + k];
  float p = 0.f;
#pragma unroll
  for (int tt = 0; tt < TWIN; ++tt) p += pos[tt * HD + k];
  v = v * (1.0f / (NG * TWIN)) + p * (1.0f / TWIN);
  sv[k] = v;
  __syncthreads();
  float a = b1[k];
#pragma unroll
  for (int kk = 0; kk < HD; ++kk) a = fmaf(sv[kk], W1[kk * HD + k], a);
  a = fmaxf(a, 0.f);
  sh1[k] = a;
  __syncthreads();
  if (k < CLS) {
    float o = b2[k];
#pragma unroll
    for (int kk = 0; kk < HD; ++kk) o = fmaf(sh1[kk], W2[kk * CLS + k], o);
    out[(size_t)b * CLS + k] = o;
  }
}

// ---------------------------------------------------------------------------
extern "C" void kernel_launch(void* const* d_in, const int* in_sizes, int n_in,
                              void* d_out, int out_size, void* d_ws, size_t ws_size,
                              hipStream_t stream) {
  const float* x      = (const float*)d_in[0];
  const int*   ei     = (const int*)  d_in[1];
  const float* W_enc  = (const float*)d_in[3];
  const float* b_enc  = (const float*)d_in[4];
  const float* ln_g   = (const float*)d_in[5];
  const float* ln_b   = (const float*)d_in[6];
  const float* W_rel  = (const float*)d_in[7];
  const float* b_rel  = (const float*)d_in[8];
  const float* W_root = (const float*)d_in[9];
  const float* pos    = (const float*)d_in[10];
  const float* W1     = (const float*)d_in[11];
  const float* b1     = (const float*)d_in[12];
  const float* W2     = (const float*)d_in[13];
  const float* b2     = (const float*)d_in[14];
  float* out = (float*)d_out;

  // workspace: W frags 320 KB | adj frags 32 MB | pooled 4.2 MB  (~36.8 MB)
  char* p = (char*)d_ws;
  unsigned* wfrag   = (unsigned*)p;  p += (size_t)LAYERS * 2 * 4 * 2 * 64 * 16;
  unsigned* adjfrag = (unsigned*)p;  p += (size_t)NGRAPH * 2 * 64 * 16;
  float*    pooled  = (float*)p;

  pack_w   <<<80, 256, 0, stream>>>(W_rel, W_root, wfrag);
  build_adj<<<NGRAPH / 4, 256, 0, stream>>>(ei, adjfrag);
  gcn_main <<<NGRAPH / 4, 256, 0, stream>>>(x, adjfrag, wfrag, W_enc, b_enc,
                                            ln_g, ln_b, b_rel, pooled);
  head     <<<BATCH, 64, 0, stream>>>(pooled, pos, W1, b1, W2, b2, out);
}

// Round 5
// 504.389 us; speedup vs baseline: 7.3393x; 1.3238x over previous
//
#include <hip/hip_runtime.h>

// Problem constants
#define NGRAPH 16384
#define NG     23
#define HD     64
#define INF    8
#define LAYERS 20
#define EDGES_PER 256
#define E_TOT  (NGRAPH * EDGES_PER)
#define BATCH  1024
#define TWIN   16
#define CLS    3

// ztr: dim-major z buffer. Row = logical dim (64 rows), NS u16 per row.
// Node position swizzled: idx = dim*NS + (node ^ (((dim>>2)&3)<<3)).
// NS=48 keeps rows 96B (16B-mult) so b128 reads stay aligned; the XOR spreads
// the 4 quads across banks (writes 2-way=free, b128 reads balanced 8/bank).
#define NS 48

typedef __attribute__((ext_vector_type(8))) short s8v;   // 8 bf16 (4 VGPRs) MFMA A/B frag
typedef __attribute__((ext_vector_type(4))) float f4v;   // 4 fp32 MFMA C/D frag

union FragU { unsigned u[4]; s8v v; };

// f32 -> packed bf16x2 (lo=a, hi=b), RNE. HW builtin if present (r4-verified
// guard), else manual RNE (r2-verified).
#if defined(__has_builtin)
#  if __has_builtin(__builtin_amdgcn_cvt_pk_bf16_f32)
#    define HAVE_CVT_PK_BF16 1
#  endif
#endif
#ifndef HAVE_CVT_PK_BF16
#  define HAVE_CVT_PK_BF16 0
#endif

__device__ inline unsigned f2bf_pk(float a, float b) {
  unsigned ua = __builtin_bit_cast(unsigned, a);
  unsigned ub = __builtin_bit_cast(unsigned, b);
  ua = ua + 0x7FFFu + ((ua >> 16) & 1u);
  ub = ub + 0x7FFFu + ((ub >> 16) & 1u);
  return (ua >> 16) | (ub & 0xFFFF0000u);
}

__device__ inline unsigned pk_bf16(float a, float b) {
#if HAVE_CVT_PK_BF16
  auto r = __builtin_amdgcn_cvt_pk_bf16_f32(a, b);
  static_assert(sizeof(r) == 4, "packed bf16x2 expected");
  return __builtin_bit_cast(unsigned, r);
#else
  return f2bf_pk(a, b);
#endif
}

// ---------------------------------------------------------------------------
// Kernel 1: edges -> adjacency B-frags (unchanged, r2-verified).
// B-frag lane map (16x16x32): value = A[dst=(lane&15)+16*Nt][src=quad*8+j].
// ---------------------------------------------------------------------------
__global__ __launch_bounds__(256) void build_adj(const int* __restrict__ ei,
                                                 unsigned* __restrict__ adjf) {
  __shared__ int cnt[4][NG * NG];
  const int grp = threadIdx.x >> 6, lane = threadIdx.x & 63;
  const int g = blockIdx.x * 4 + grp;
  for (int i = lane; i < NG * NG; i += 64) cnt[grp][i] = 0;
  __syncthreads();
  const int base = g * EDGES_PER, goff = g * NG;
#pragma unroll
  for (int r = 0; r < EDGES_PER / 64; ++r) {
    const int e = base + r * 64 + lane;
    atomicAdd(&cnt[grp][(ei[E_TOT + e] - goff) * NG + (ei[e] - goff)], 1);
  }
  __syncthreads();
  const int col = lane & 15, quad = lane >> 4;
#pragma unroll
  for (int Nt = 0; Nt < 2; ++Nt) {
    const int dst = col + 16 * Nt;
    unsigned pk[4];
#pragma unroll
    for (int w = 0; w < 4; ++w) {
      const int s0 = quad * 8 + 2 * w, s1 = s0 + 1;
      float v0 = 0.f, v1 = 0.f;
      if (dst < NG) {
        if (s0 < NG) v0 = (float)cnt[grp][dst * NG + s0];
        if (s1 < NG) v1 = (float)cnt[grp][dst * NG + s1];
      }
      pk[w] = f2bf_pk(v0, v1);
    }
    uint4 q; q.x = pk[0]; q.y = pk[1]; q.z = pk[2]; q.w = pk[3];
    *(uint4*)&adjf[(((size_t)g * 2 + Nt) * 64 + lane) * 4] = q;
  }
}

// ---------------------------------------------------------------------------
// Kernel 2: pack W^T into A-frag order with the PERMUTED k-mapping.
// k-slot (Kt, quad, j) holds logical dim_in = ((j>>2)*2+Kt)*16 + quad*4 + (j&3)
// — chosen so the C-frag layout of z/agg doubles as the B-frag (in-register).
// ---------------------------------------------------------------------------
__global__ __launch_bounds__(256) void pack_w(const float* __restrict__ W_rel,
                                              const float* __restrict__ W_root,
                                              unsigned* __restrict__ wf) {
  const int tid = blockIdx.x * 256 + threadIdx.x;
  if (tid >= LAYERS * 2 * 4 * 2 * 64) return;
  const int lane = tid & 63, fi = tid >> 6;
  const int Kt = fi & 1, Mt = (fi >> 1) & 3, m = (fi >> 3) & 1, l = fi >> 4;
  const float* W = (m ? W_root : W_rel) + (size_t)l * HD * HD;
  const int col = lane & 15, quad = lane >> 4;
  const int jdim = Mt * 16 + col;   // output dim (A-frag m-index), natural
  unsigned pk[4];
#pragma unroll
  for (int w = 0; w < 4; ++w) {
    const int j0 = 2 * w, j1 = 2 * w + 1;
    const int d0 = ((j0 >> 2) * 2 + Kt) * 16 + quad * 4 + (j0 & 3);
    const int d1 = ((j1 >> 2) * 2 + Kt) * 16 + quad * 4 + (j1 & 3);
    pk[w] = f2bf_pk(W[(size_t)d0 * HD + jdim], W[(size_t)d1 * HD + jdim]);
  }
  uint4 q; q.x = pk[0]; q.y = pk[1]; q.z = pk[2]; q.w = pk[3];
  *(uint4*)&wf[(size_t)tid * 4] = q;
}

// ---------------------------------------------------------------------------
// Kernel 3: wave = 1 graph. H in 8 fp32 C-frags. Per layer:
//   LN -> z (C-layout regs) -> in-register B-frags (zpk) + ztr scatter
//   -> Wo-GEMM (no LDS dep) -> fence -> za b128 reads -> agg GEMM
//   -> in-register B-frags (apk) -> Wr-GEMM -> +br.
// Single lgkm fence per layer; zbuf/aggbuf LDS round-trips eliminated.
// ---------------------------------------------------------------------------
__global__ __launch_bounds__(256) void gcn_main(
    const float* __restrict__ x, const unsigned* __restrict__ adjf,
    const unsigned* __restrict__ wf,
    const float* __restrict__ W_enc, const float* __restrict__ b_enc,
    const float* __restrict__ ln_g, const float* __restrict__ ln_b,
    const float* __restrict__ b_rel, float* __restrict__ pooled) {
  __shared__ __align__(16) unsigned short sm[4 * HD * NS];   // 24576 B/block
  const int lane = threadIdx.x & 63, wv = threadIdx.x >> 6;
  const int g = blockIdx.x * 4 + wv;
  const int col = lane & 15, quad = lane >> 4;
  unsigned short* zt = sm + wv * (HD * NS);

  // adjacency B-frags, persistent across layers
  const s8v adjB0 = *(const s8v*)&adjf[(((size_t)g * 2 + 0) * 64 + lane) * 4];
  const s8v adjB1 = *(const s8v*)&adjf[(((size_t)g * 2 + 1) * 64 + lane) * 4];

  // swizzled node positions for ztr writes (dim rows of this lane have
  // (dim>>2)&3 == quad)
  const int nsw[2] = { col ^ (quad << 3), (col + 16) ^ (quad << 3) };

  // ---- encoder: H[d][n] = sum_i W_enc[i][d] x[n][i] + b_enc[d] ----
  f4v acc[4][2];
  {
    f4v xa[2][2];
    const f4v zz = {0.f, 0.f, 0.f, 0.f};
#pragma unroll
    for (int Nt = 0; Nt < 2; ++Nt) {
      const int n = col + 16 * Nt;
      if (n < NG) {
        const float* xp = x + ((size_t)g * NG + n) * INF;
        xa[Nt][0] = *(const f4v*)xp;
        xa[Nt][1] = *(const f4v*)(xp + 4);
      } else { xa[Nt][0] = zz; xa[Nt][1] = zz; }
    }
#pragma unroll
    for (int Mt = 0; Mt < 4; ++Mt) {
      const f4v be = *(const f4v*)(b_enc + Mt * 16 + quad * 4);
      acc[Mt][0] = be; acc[Mt][1] = be;
#pragma unroll
      for (int i = 0; i < INF; ++i) {
        const f4v we = *(const f4v*)(W_enc + i * HD + Mt * 16 + quad * 4);
        acc[Mt][0] += we * xa[0][i >> 2][i & 3];
        acc[Mt][1] += we * xa[1][i >> 2][i & 3];
      }
    }
  }

#pragma unroll 1
  for (int l = 0; l < LAYERS; ++l) {
    const unsigned* wbase = wf + (size_t)l * (2 * 4 * 2 * 64 * 4);
    f4v gf[4], bfv[4];
#pragma unroll
    for (int Mt = 0; Mt < 4; ++Mt) {
      gf[Mt]  = *(const f4v*)(ln_g + l * HD + Mt * 16 + quad * 4);
      bfv[Mt] = *(const f4v*)(ln_b + l * HD + Mt * 16 + quad * 4);
    }

    // ---- LayerNorm per node-col: one-pass E[h], E[h^2] (r4-verified) ----
    float mu[2], rs[2];
    {
      float sh[2], qh[2];
#pragma unroll
      for (int Nt = 0; Nt < 2; ++Nt) {
        f4v t = acc[0][Nt] + acc[1][Nt];
        t += acc[2][Nt]; t += acc[3][Nt];
        f4v u = acc[0][Nt] * acc[0][Nt];
        u += acc[1][Nt] * acc[1][Nt];
        u += acc[2][Nt] * acc[2][Nt];
        u += acc[3][Nt] * acc[3][Nt];
        sh[Nt] = (t[0] + t[1]) + (t[2] + t[3]);
        qh[Nt] = (u[0] + u[1]) + (u[2] + u[3]);
      }
      sh[0] += __shfl_xor(sh[0], 16); sh[1] += __shfl_xor(sh[1], 16);
      qh[0] += __shfl_xor(qh[0], 16); qh[1] += __shfl_xor(qh[1], 16);
      sh[0] += __shfl_xor(sh[0], 32); sh[1] += __shfl_xor(sh[1], 32);
      qh[0] += __shfl_xor(qh[0], 32); qh[1] += __shfl_xor(qh[1], 32);
#pragma unroll
      for (int Nt = 0; Nt < 2; ++Nt) {
        mu[Nt] = sh[Nt] * (1.0f / HD);
        float var = fmaf(qh[Nt], (1.0f / HD), -mu[Nt] * mu[Nt]);
        var = fmaxf(var, 0.f);
        rs[Nt] = rsqrtf(var + 1e-5f);
      }
    }

    // ---- z = relu(LN(h)); pack B-frags in-register + ztr scatter ----
    FragU zpk[2][2];   // [Kt][Nt] : B-frag of Z under the k-permutation
#pragma unroll
    for (int Kt = 0; Kt < 2; ++Kt) {
      f4v zq[2][2];    // [hi][Nt], Mt = Kt + 2*hi
#pragma unroll
      for (int hi = 0; hi < 2; ++hi) {
        const int Mt = Kt + 2 * hi;
#pragma unroll
        for (int Nt = 0; Nt < 2; ++Nt) {
          const f4v sg = gf[Mt] * rs[Nt];
          const f4v tb = bfv[Mt] - mu[Nt] * sg;
          f4v z4 = acc[Mt][Nt] * sg + tb;
          z4[0] = fmaxf(z4[0], 0.f); z4[1] = fmaxf(z4[1], 0.f);
          z4[2] = fmaxf(z4[2], 0.f); z4[3] = fmaxf(z4[3], 0.f);
          zq[hi][Nt] = z4;
        }
      }
#pragma unroll
      for (int Nt = 0; Nt < 2; ++Nt) {
        zpk[Kt][Nt].u[0] = pk_bf16(zq[0][Nt][0], zq[0][Nt][1]);
        zpk[Kt][Nt].u[1] = pk_bf16(zq[0][Nt][2], zq[0][Nt][3]);
        zpk[Kt][Nt].u[2] = pk_bf16(zq[1][Nt][0], zq[1][Nt][1]);
        zpk[Kt][Nt].u[3] = pk_bf16(zq[1][Nt][2], zq[1][Nt][3]);
      }
      // ztr scatter (b16 writes; reuse packed dwords, shift for odd dims)
#pragma unroll
      for (int hi = 0; hi < 2; ++hi) {
        const int Mt = Kt + 2 * hi;
        const int dbase = Mt * 16 + quad * 4;
#pragma unroll
        for (int Nt = 0; Nt < 2; ++Nt)
#pragma unroll
          for (int r2 = 0; r2 < 2; ++r2) {
            const unsigned d = zpk[Kt][Nt].u[hi * 2 + r2];
            zt[(dbase + 2 * r2    ) * NS + nsw[Nt]] = (unsigned short)d;
            zt[(dbase + 2 * r2 + 1) * NS + nsw[Nt]] = (unsigned short)(d >> 16);
          }
      }
    }

    // ---- Wo-GEMM: H += Wo^T @ Z (register B — overlaps ztr round-trip) ----
#pragma unroll
    for (int Kt = 0; Kt < 2; ++Kt)
#pragma unroll
      for (int Mt = 0; Mt < 4; ++Mt) {
        const s8v wo = *(const s8v*)&wbase[((((1 * 4) + Mt) * 2 + Kt) * 64 + lane) * 4];
#pragma unroll
        for (int Nt = 0; Nt < 2; ++Nt)
          acc[Mt][Nt] = __builtin_amdgcn_mfma_f32_16x16x32_bf16(wo, zpk[Kt][Nt].v, acc[Mt][Nt], 0, 0, 0);
      }

    asm volatile("s_waitcnt lgkmcnt(0)" ::: "memory");

    // ---- Z as A-frag: 4 aligned ds_read_b128 (swizzle-balanced) ----
    FragU za[4];
#pragma unroll
    for (int Mt = 0; Mt < 4; ++Mt) {
      const int dim = Mt * 16 + col;
      const int qq = (quad ^ (col >> 2)) * 8;
      za[Mt].v = *(const s8v*)&zt[dim * NS + qq];
    }

    // ---- AGG = Z @ A^T ----
    const f4v zzero = {0.f, 0.f, 0.f, 0.f};
    f4v ag[4][2];
#pragma unroll
    for (int Mt = 0; Mt < 4; ++Mt) {
      ag[Mt][0] = __builtin_amdgcn_mfma_f32_16x16x32_bf16(za[Mt].v, adjB0, zzero, 0, 0, 0);
      ag[Mt][1] = __builtin_amdgcn_mfma_f32_16x16x32_bf16(za[Mt].v, adjB1, zzero, 0, 0, 0);
    }

    // ---- AGG -> B-frags in-register ----
    FragU apk[2][2];
#pragma unroll
    for (int Kt = 0; Kt < 2; ++Kt)
#pragma unroll
      for (int Nt = 0; Nt < 2; ++Nt) {
        apk[Kt][Nt].u[0] = pk_bf16(ag[Kt    ][Nt][0], ag[Kt    ][Nt][1]);
        apk[Kt][Nt].u[1] = pk_bf16(ag[Kt    ][Nt][2], ag[Kt    ][Nt][3]);
        apk[Kt][Nt].u[2] = pk_bf16(ag[Kt + 2][Nt][0], ag[Kt + 2][Nt][1]);
        apk[Kt][Nt].u[3] = pk_bf16(ag[Kt + 2][Nt][2], ag[Kt + 2][Nt][3]);
      }

    // ---- Wr-GEMM: H += Wr^T @ AGG ----
#pragma unroll
    for (int Kt = 0; Kt < 2; ++Kt)
#pragma unroll
      for (int Mt = 0; Mt < 4; ++Mt) {
        const s8v wr = *(const s8v*)&wbase[((((0 * 4) + Mt) * 2 + Kt) * 64 + lane) * 4];
#pragma unroll
        for (int Nt = 0; Nt < 2; ++Nt)
          acc[Mt][Nt] = __builtin_amdgcn_mfma_f32_16x16x32_bf16(wr, apk[Kt][Nt].v, acc[Mt][Nt], 0, 0, 0);
      }

    // ---- + b_rel ----
#pragma unroll
    for (int Mt = 0; Mt < 4; ++Mt) {
      const f4v brf = *(const f4v*)(b_rel + l * HD + Mt * 16 + quad * 4);
      acc[Mt][0] += brf;
      acc[Mt][1] += brf;
    }
  }

  // ---- pool: sum over 23 real node-cols per dim (reuse zt as f32) ----
  float* hb = (float*)zt;   // 6144 B wave region >= 23*64*4 = 5888 B
  asm volatile("s_waitcnt lgkmcnt(0)" ::: "memory");
#pragma unroll
  for (int Mt = 0; Mt < 4; ++Mt)
#pragma unroll
    for (int Nt = 0; Nt < 2; ++Nt) {
      const int n = col + 16 * Nt;
      if (n < NG) *(f4v*)&hb[n * HD + Mt * 16 + quad * 4] = acc[Mt][Nt];
    }
  asm volatile("s_waitcnt lgkmcnt(0)" ::: "memory");
  float s = 0.f;
#pragma unroll
  for (int n = 0; n < NG; ++n) s += hb[n * HD + lane];
  pooled[(size_t)g * HD + lane] = s;
}

// ---------------------------------------------------------------------------
// Kernel 4: temporal mean (+pos) + MLP head (unchanged, verified)
// ---------------------------------------------------------------------------
__global__ __launch_bounds__(64) void head(
    const float* __restrict__ pooled, const float* __restrict__ pos,
    const float* __restrict__ W1, const float* __restrict__ b1,
    const float* __restrict__ W2, const float* __restrict__ b2,
    float* __restrict__ out) {
  __shared__ float sv[HD];
  __shared__ float sh1[HD];
  const int b = blockIdx.x, k = threadIdx.x;
  float v = 0.f;
#pragma unroll
  for (int tt = 0; tt < TWIN; ++tt) v += pooled[((size_t)(b * TWIN + tt)) * HD + k];
  float p = 0.f;
#pragma unroll
  for (int tt = 0; tt < TWIN; ++tt) p += pos[tt * HD + k];
  v = v * (1.0f / (NG * TWIN)) + p * (1.0f / TWIN);
  sv[k] = v;
  __syncthreads();
  float a = b1[k];
#pragma unroll
  for (int kk = 0; kk < HD; ++kk) a = fmaf(sv[kk], W1[kk * HD + k], a);
  a = fmaxf(a, 0.f);
  sh1[k] = a;
  __syncthreads();
  if (k < CLS) {
    float o = b2[k];
#pragma unroll
    for (int kk = 0; kk < HD; ++kk) o = fmaf(sh1[kk], W2[kk * CLS + k], o);
    out[(size_t)b * CLS + k] = o;
  }
}

// ---------------------------------------------------------------------------
extern "C" void kernel_launch(void* const* d_in, const int* in_sizes, int n_in,
                              void* d_out, int out_size, void* d_ws, size_t ws_size,
                              hipStream_t stream) {
  const float* x      = (const float*)d_in[0];
  const int*   ei     = (const int*)  d_in[1];
  const float* W_enc  = (const float*)d_in[3];
  const float* b_enc  = (const float*)d_in[4];
  const float* ln_g   = (const float*)d_in[5];
  const float* ln_b   = (const float*)d_in[6];
  const float* W_rel  = (const float*)d_in[7];
  const float* b_rel  = (const float*)d_in[8];
  const float* W_root = (const float*)d_in[9];
  const float* pos    = (const float*)d_in[10];
  const float* W1     = (const float*)d_in[11];
  const float* b1     = (const float*)d_in[12];
  const float* W2     = (const float*)d_in[13];
  const float* b2     = (const float*)d_in[14];
  float* out = (float*)d_out;

  // workspace: W frags 320 KB | adj frags 32 MB | pooled 4.2 MB
  char* p = (char*)d_ws;
  unsigned* wfrag   = (unsigned*)p;  p += (size_t)LAYERS * 2 * 4 * 2 * 64 * 16;
  unsigned* adjfrag = (unsigned*)p;  p += (size_t)NGRAPH * 2 * 64 * 16;
  float*    pooled  = (float*)p;

  pack_w   <<<80, 256, 0, stream>>>(W_rel, W_root, wfrag);
  build_adj<<<NGRAPH / 4, 256, 0, stream>>>(ei, adjfrag);
  gcn_main <<<NGRAPH / 4, 256, 0, stream>>>(x, adjfrag, wfrag, W_enc, b_enc,
                                            ln_g, ln_b, b_rel, pooled);
  head     <<<BATCH, 64, 0, stream>>>(pooled, pos, W1, b1, W2, b2, out);
}

// Round 7
// 464.243 us; speedup vs baseline: 7.9739x; 1.0865x over previous
//
#include <hip/hip_runtime.h>
#include <hip/hip_bf16.h>

// Problem constants
#define NGRAPH 16384
#define NG     23
#define HD     64
#define INF    8
#define LAYERS 20
#define EDGES_PER 256
#define E_TOT  (NGRAPH * EDGES_PER)
#define BATCH  1024
#define TWIN   16
#define CLS    3

// ztr: dim-major z buffer (r5-verified). Row = logical dim, NS u16 per row,
// node position swizzled: idx = dim*NS + (node ^ (((dim>>2)&3)<<3)).
#define NS 48

typedef __attribute__((ext_vector_type(8))) short s8v;   // 8 bf16 MFMA A/B frag
typedef __attribute__((ext_vector_type(4))) float f4v;   // 4 fp32 MFMA C/D frag
typedef __attribute__((ext_vector_type(2))) float f2v;   // packed-fp32 pair

union FragU { unsigned u[4]; s8v v; };

__device__ inline f2v vlo(f4v v) { return (f2v){v[0], v[1]}; }
__device__ inline f2v vhi(f4v v) { return (f2v){v[2], v[3]}; }

// HW RNE f32x2 -> bf16x2 via documented HIP API (lowers to v_cvt_pk_bf16_f32).
// Bits extracted with memcpy: __hip_bfloat162 is not trivially copyable on
// this ROCm, so __builtin_bit_cast is ill-formed (r6 compile failure).
__device__ inline unsigned pk2_bf16(f2v v) {
  __hip_bfloat162 b = __float22bfloat162_rn(make_float2(v[0], v[1]));
  unsigned r;
  __builtin_memcpy(&r, &b, sizeof(r));
  return r;
}

__device__ inline f2v max0(f2v v) {
#if defined(__has_builtin) && __has_builtin(__builtin_elementwise_max)
  return __builtin_elementwise_max(v, (f2v){0.f, 0.f});
#else
  return (f2v){fmaxf(v[0], 0.f), fmaxf(v[1], 0.f)};
#endif
}

// manual RNE pack (cold prep kernels only)
__device__ inline unsigned f2bf_pk(float a, float b) {
  unsigned ua = __builtin_bit_cast(unsigned, a);
  unsigned ub = __builtin_bit_cast(unsigned, b);
  ua = ua + 0x7FFFu + ((ua >> 16) & 1u);
  ub = ub + 0x7FFFu + ((ub >> 16) & 1u);
  return (ua >> 16) | (ub & 0xFFFF0000u);
}

// ---------------------------------------------------------------------------
// Kernel 1: edges -> adjacency B-frags (unchanged, r2-verified).
// ---------------------------------------------------------------------------
__global__ __launch_bounds__(256) void build_adj(const int* __restrict__ ei,
                                                 unsigned* __restrict__ adjf) {
  __shared__ int cnt[4][NG * NG];
  const int grp = threadIdx.x >> 6, lane = threadIdx.x & 63;
  const int g = blockIdx.x * 4 + grp;
  for (int i = lane; i < NG * NG; i += 64) cnt[grp][i] = 0;
  __syncthreads();
  const int base = g * EDGES_PER, goff = g * NG;
#pragma unroll
  for (int r = 0; r < EDGES_PER / 64; ++r) {
    const int e = base + r * 64 + lane;
    atomicAdd(&cnt[grp][(ei[E_TOT + e] - goff) * NG + (ei[e] - goff)], 1);
  }
  __syncthreads();
  const int col = lane & 15, quad = lane >> 4;
#pragma unroll
  for (int Nt = 0; Nt < 2; ++Nt) {
    const int dst = col + 16 * Nt;
    unsigned pk[4];
#pragma unroll
    for (int w = 0; w < 4; ++w) {
      const int s0 = quad * 8 + 2 * w, s1 = s0 + 1;
      float v0 = 0.f, v1 = 0.f;
      if (dst < NG) {
        if (s0 < NG) v0 = (float)cnt[grp][dst * NG + s0];
        if (s1 < NG) v1 = (float)cnt[grp][dst * NG + s1];
      }
      pk[w] = f2bf_pk(v0, v1);
    }
    uint4 q; q.x = pk[0]; q.y = pk[1]; q.z = pk[2]; q.w = pk[3];
    *(uint4*)&adjf[(((size_t)g * 2 + Nt) * 64 + lane) * 4] = q;
  }
}

// ---------------------------------------------------------------------------
// Kernel 2: pack W^T into A-frag order, permuted k-mapping (r5-verified):
// k-slot (Kt, quad, j) holds dim_in = ((j>>2)*2+Kt)*16 + quad*4 + (j&3).
// ---------------------------------------------------------------------------
__global__ __launch_bounds__(256) void pack_w(const float* __restrict__ W_rel,
                                              const float* __restrict__ W_root,
                                              unsigned* __restrict__ wf) {
  const int tid = blockIdx.x * 256 + threadIdx.x;
  if (tid >= LAYERS * 2 * 4 * 2 * 64) return;
  const int lane = tid & 63, fi = tid >> 6;
  const int Kt = fi & 1, Mt = (fi >> 1) & 3, m = (fi >> 3) & 1, l = fi >> 4;
  const float* W = (m ? W_root : W_rel) + (size_t)l * HD * HD;
  const int col = lane & 15, quad = lane >> 4;
  const int jdim = Mt * 16 + col;
  unsigned pk[4];
#pragma unroll
  for (int w = 0; w < 4; ++w) {
    const int j0 = 2 * w, j1 = 2 * w + 1;
    const int d0 = ((j0 >> 2) * 2 + Kt) * 16 + quad * 4 + (j0 & 3);
    const int d1 = ((j1 >> 2) * 2 + Kt) * 16 + quad * 4 + (j1 & 3);
    pk[w] = f2bf_pk(W[(size_t)d0 * HD + jdim], W[(size_t)d1 * HD + jdim]);
  }
  uint4 q; q.x = pk[0]; q.y = pk[1]; q.z = pk[2]; q.w = pk[3];
  *(uint4*)&wf[(size_t)tid * 4] = q;
}

// ---------------------------------------------------------------------------
// Kernel 3: wave = 1 graph. H in 8 fp32 C-frags; per layer: LN -> z (f2v
// packed math) -> in-register B-frags + ztr scatter -> Wo-GEMM -> fence ->
// za b128 -> agg GEMM -> apk/Wr interleaved -> +br. (r5 structure, VALU diet)
// ---------------------------------------------------------------------------
__global__ __launch_bounds__(256) void gcn_main(
    const float* __restrict__ x, const unsigned* __restrict__ adjf,
    const unsigned* __restrict__ wf,
    const float* __restrict__ W_enc, const float* __restrict__ b_enc,
    const float* __restrict__ ln_g, const float* __restrict__ ln_b,
    const float* __restrict__ b_rel, float* __restrict__ pooled) {
  __shared__ __align__(16) unsigned short sm[4 * HD * NS];   // 24576 B/block
  const int lane = threadIdx.x & 63, wv = threadIdx.x >> 6;
  const int g = blockIdx.x * 4 + wv;
  const int col = lane & 15, quad = lane >> 4;
  unsigned short* zt = sm + wv * (HD * NS);

  const s8v adjB0 = *(const s8v*)&adjf[(((size_t)g * 2 + 0) * 64 + lane) * 4];
  const s8v adjB1 = *(const s8v*)&adjf[(((size_t)g * 2 + 1) * 64 + lane) * 4];

  const int nsw[2] = { col ^ (quad << 3), (col + 16) ^ (quad << 3) };

  // ---- encoder ----
  f4v acc[4][2];
  {
    f4v xa[2][2];
    const f4v zz = {0.f, 0.f, 0.f, 0.f};
#pragma unroll
    for (int Nt = 0; Nt < 2; ++Nt) {
      const int n = col + 16 * Nt;
      if (n < NG) {
        const float* xp = x + ((size_t)g * NG + n) * INF;
        xa[Nt][0] = *(const f4v*)xp;
        xa[Nt][1] = *(const f4v*)(xp + 4);
      } else { xa[Nt][0] = zz; xa[Nt][1] = zz; }
    }
#pragma unroll
    for (int Mt = 0; Mt < 4; ++Mt) {
      const f4v be = *(const f4v*)(b_enc + Mt * 16 + quad * 4);
      acc[Mt][0] = be; acc[Mt][1] = be;
#pragma unroll
      for (int i = 0; i < INF; ++i) {
        const f4v we = *(const f4v*)(W_enc + i * HD + Mt * 16 + quad * 4);
        acc[Mt][0] += we * xa[0][i >> 2][i & 3];
        acc[Mt][1] += we * xa[1][i >> 2][i & 3];
      }
    }
  }

#pragma unroll 1
  for (int l = 0; l < LAYERS; ++l) {
    const unsigned* wbase = wf + (size_t)l * (2 * 4 * 2 * 64 * 4);
    f4v gf[4], bfv[4];
#pragma unroll
    for (int Mt = 0; Mt < 4; ++Mt) {
      gf[Mt]  = *(const f4v*)(ln_g + l * HD + Mt * 16 + quad * 4);
      bfv[Mt] = *(const f4v*)(ln_b + l * HD + Mt * 16 + quad * 4);
    }

    // ---- LayerNorm: one-pass E[h], E[h^2] in f2v (packed fp32) ----
    float mu[2], rs[2];
    {
      float sh[2], qh[2];
#pragma unroll
      for (int Nt = 0; Nt < 2; ++Nt) {
        f2v t = vlo(acc[0][Nt]) + vhi(acc[0][Nt]);
        t += vlo(acc[1][Nt]); t += vhi(acc[1][Nt]);
        t += vlo(acc[2][Nt]); t += vhi(acc[2][Nt]);
        t += vlo(acc[3][Nt]); t += vhi(acc[3][Nt]);
        f2v u = vlo(acc[0][Nt]) * vlo(acc[0][Nt]);
        u += vhi(acc[0][Nt]) * vhi(acc[0][Nt]);
        u += vlo(acc[1][Nt]) * vlo(acc[1][Nt]);
        u += vhi(acc[1][Nt]) * vhi(acc[1][Nt]);
        u += vlo(acc[2][Nt]) * vlo(acc[2][Nt]);
        u += vhi(acc[2][Nt]) * vhi(acc[2][Nt]);
        u += vlo(acc[3][Nt]) * vlo(acc[3][Nt]);
        u += vhi(acc[3][Nt]) * vhi(acc[3][Nt]);
        sh[Nt] = t[0] + t[1];
        qh[Nt] = u[0] + u[1];
      }
      sh[0] += __shfl_xor(sh[0], 16); sh[1] += __shfl_xor(sh[1], 16);
      qh[0] += __shfl_xor(qh[0], 16); qh[1] += __shfl_xor(qh[1], 16);
      sh[0] += __shfl_xor(sh[0], 32); sh[1] += __shfl_xor(sh[1], 32);
      qh[0] += __shfl_xor(qh[0], 32); qh[1] += __shfl_xor(qh[1], 32);
#pragma unroll
      for (int Nt = 0; Nt < 2; ++Nt) {
        mu[Nt] = sh[Nt] * (1.0f / HD);
        float var = fmaf(qh[Nt], (1.0f / HD), -mu[Nt] * mu[Nt]);
        var = fmaxf(var, 0.f);
        rs[Nt] = rsqrtf(var + 1e-5f);
      }
    }

    // ---- z = relu(h*(rs*g) + (b - mu*rs*g)), f2v math, HW bf16 pack ----
    FragU zpk[2][2];   // [Kt][Nt]: B-frag of Z under the k-permutation
#pragma unroll
    for (int Kt = 0; Kt < 2; ++Kt) {
#pragma unroll
      for (int hi = 0; hi < 2; ++hi) {
        const int Mt = Kt + 2 * hi;
        const f2v gl = vlo(gf[Mt]), gh = vhi(gf[Mt]);
        const f2v bl = vlo(bfv[Mt]), bh = vhi(bfv[Mt]);
#pragma unroll
        for (int Nt = 0; Nt < 2; ++Nt) {
          const f2v sgl = gl * rs[Nt], sgh = gh * rs[Nt];
          const f2v tbl = bl - mu[Nt] * sgl, tbh = bh - mu[Nt] * sgh;
          const f2v zl = max0(vlo(acc[Mt][Nt]) * sgl + tbl);
          const f2v zh = max0(vhi(acc[Mt][Nt]) * sgh + tbh);
          zpk[Kt][Nt].u[hi * 2 + 0] = pk2_bf16(zl);
          zpk[Kt][Nt].u[hi * 2 + 1] = pk2_bf16(zh);
        }
      }
      // ztr scatter (b16 writes from the packed dwords)
#pragma unroll
      for (int hi = 0; hi < 2; ++hi) {
        const int Mt = Kt + 2 * hi;
        const int dbase = Mt * 16 + quad * 4;
#pragma unroll
        for (int Nt = 0; Nt < 2; ++Nt)
#pragma unroll
          for (int r2 = 0; r2 < 2; ++r2) {
            const unsigned d = zpk[Kt][Nt].u[hi * 2 + r2];
            zt[(dbase + 2 * r2    ) * NS + nsw[Nt]] = (unsigned short)d;
            zt[(dbase + 2 * r2 + 1) * NS + nsw[Nt]] = (unsigned short)(d >> 16);
          }
      }
    }

    // ---- Wo-GEMM (register B; overlaps the ztr round-trip) ----
#pragma unroll
    for (int Kt = 0; Kt < 2; ++Kt)
#pragma unroll
      for (int Mt = 0; Mt < 4; ++Mt) {
        const s8v wo = *(const s8v*)&wbase[((((1 * 4) + Mt) * 2 + Kt) * 64 + lane) * 4];
#pragma unroll
        for (int Nt = 0; Nt < 2; ++Nt)
          acc[Mt][Nt] = __builtin_amdgcn_mfma_f32_16x16x32_bf16(wo, zpk[Kt][Nt].v, acc[Mt][Nt], 0, 0, 0);
      }

    asm volatile("s_waitcnt lgkmcnt(0)" ::: "memory");

    // ---- Z as A-frag: 4 aligned ds_read_b128 (swizzle-balanced) ----
    FragU za[4];
#pragma unroll
    for (int Mt = 0; Mt < 4; ++Mt) {
      const int dim = Mt * 16 + col;
      const int qq = (quad ^ (col >> 2)) * 8;
      za[Mt].v = *(const s8v*)&zt[dim * NS + qq];
    }

    // ---- AGG = Z @ A^T ----
    const f4v zzero = {0.f, 0.f, 0.f, 0.f};
    f4v ag[4][2];
#pragma unroll
    for (int Mt = 0; Mt < 4; ++Mt) {
      ag[Mt][0] = __builtin_amdgcn_mfma_f32_16x16x32_bf16(za[Mt].v, adjB0, zzero, 0, 0, 0);
      ag[Mt][1] = __builtin_amdgcn_mfma_f32_16x16x32_bf16(za[Mt].v, adjB1, zzero, 0, 0, 0);
    }

    // ---- apk pack + Wr-GEMM, interleaved per Kt ----
#pragma unroll
    for (int Kt = 0; Kt < 2; ++Kt) {
      FragU apk[2];
#pragma unroll
      for (int Nt = 0; Nt < 2; ++Nt) {
        apk[Nt].u[0] = pk2_bf16(vlo(ag[Kt    ][Nt]));
        apk[Nt].u[1] = pk2_bf16(vhi(ag[Kt    ][Nt]));
        apk[Nt].u[2] = pk2_bf16(vlo(ag[Kt + 2][Nt]));
        apk[Nt].u[3] = pk2_bf16(vhi(ag[Kt + 2][Nt]));
      }
#pragma unroll
      for (int Mt = 0; Mt < 4; ++Mt) {
        const s8v wr = *(const s8v*)&wbase[((((0 * 4) + Mt) * 2 + Kt) * 64 + lane) * 4];
#pragma unroll
        for (int Nt = 0; Nt < 2; ++Nt)
          acc[Mt][Nt] = __builtin_amdgcn_mfma_f32_16x16x32_bf16(wr, apk[Nt].v, acc[Mt][Nt], 0, 0, 0);
      }
    }

    // ---- + b_rel (f2v packed adds) ----
#pragma unroll
    for (int Mt = 0; Mt < 4; ++Mt) {
      const f4v brf = *(const f4v*)(b_rel + l * HD + Mt * 16 + quad * 4);
      const f2v bl = vlo(brf), bh = vhi(brf);
#pragma unroll
      for (int Nt = 0; Nt < 2; ++Nt) {
        const f2v al = vlo(acc[Mt][Nt]) + bl;
        const f2v ah = vhi(acc[Mt][Nt]) + bh;
        acc[Mt][Nt] = (f4v){al[0], al[1], ah[0], ah[1]};
      }
    }
  }

  // ---- pool: sum over 23 real node-cols per dim (reuse zt as f32) ----
  float* hb = (float*)zt;
  asm volatile("s_waitcnt lgkmcnt(0)" ::: "memory");
#pragma unroll
  for (int Mt = 0; Mt < 4; ++Mt)
#pragma unroll
    for (int Nt = 0; Nt < 2; ++Nt) {
      const int n = col + 16 * Nt;
      if (n < NG) *(f4v*)&hb[n * HD + Mt * 16 + quad * 4] = acc[Mt][Nt];
    }
  asm volatile("s_waitcnt lgkmcnt(0)" ::: "memory");
  float s = 0.f;
#pragma unroll
  for (int n = 0; n < NG; ++n) s += hb[n * HD + lane];
  pooled[(size_t)g * HD + lane] = s;
}

// ---------------------------------------------------------------------------
// Kernel 4: temporal mean (+pos) + MLP head (unchanged, verified)
// ---------------------------------------------------------------------------
__global__ __launch_bounds__(64) void head(
    const float* __restrict__ pooled, const float* __restrict__ pos,
    const float* __restrict__ W1, const float* __restrict__ b1,
    const float* __restrict__ W2, const float* __restrict__ b2,
    float* __restrict__ out) {
  __shared__ float sv[HD];
  __shared__ float sh1[HD];
  const int b = blockIdx.x, k = threadIdx.x;
  float v = 0.f;
#pragma unroll
  for (int tt = 0; tt < TWIN; ++tt) v += pooled[((size_t)(b * TWIN + tt)) * HD + k];
  float p = 0.f;
#pragma unroll
  for (int tt = 0; tt < TWIN; ++tt) p += pos[tt * HD + k];
  v = v * (1.0f / (NG * TWIN)) + p * (1.0f / TWIN);
  sv[k] = v;
  __syncthreads();
  float a = b1[k];
#pragma unroll
  for (int kk = 0; kk < HD; ++kk) a = fmaf(sv[kk], W1[kk * HD + k], a);
  a = fmaxf(a, 0.f);
  sh1[k] = a;
  __syncthreads();
  if (k < CLS) {
    float o = b2[k];
#pragma unroll
    for (int kk = 0; kk < HD; ++kk) o = fmaf(sh1[kk], W2[kk * CLS + k], o);
    out[(size_t)b * CLS + k] = o;
  }
}

// ---------------------------------------------------------------------------
extern "C" void kernel_launch(void* const* d_in, const int* in_sizes, int n_in,
                              void* d_out, int out_size, void* d_ws, size_t ws_size,
                              hipStream_t stream) {
  const float* x      = (const float*)d_in[0];
  const int*   ei     = (const int*)  d_in[1];
  const float* W_enc  = (const float*)d_in[3];
  const float* b_enc  = (const float*)d_in[4];
  const float* ln_g   = (const float*)d_in[5];
  const float* ln_b   = (const float*)d_in[6];
  const float* W_rel  = (const float*)d_in[7];
  const float* b_rel  = (const float*)d_in[8];
  const float* W_root = (const float*)d_in[9];
  const float* pos    = (const float*)d_in[10];
  const float* W1     = (const float*)d_in[11];
  const float* b1     = (const float*)d_in[12];
  const float* W2     = (const float*)d_in[13];
  const float* b2     = (const float*)d_in[14];
  float* out = (float*)d_out;

  char* p = (char*)d_ws;
  unsigned* wfrag   = (unsigned*)p;  p += (size_t)LAYERS * 2 * 4 * 2 * 64 * 16;
  unsigned* adjfrag = (unsigned*)p;  p += (size_t)NGRAPH * 2 * 64 * 16;
  float*    pooled  = (float*)p;

  pack_w   <<<80, 256, 0, stream>>>(W_rel, W_root, wfrag);
  build_adj<<<NGRAPH / 4, 256, 0, stream>>>(ei, adjfrag);
  gcn_main <<<NGRAPH / 4, 256, 0, stream>>>(x, adjfrag, wfrag, W_enc, b_enc,
                                            ln_g, ln_b, b_rel, pooled);
  head     <<<BATCH, 64, 0, stream>>>(pooled, pos, W1, b1, W2, b2, out);
}